// Round 1
// baseline (6919.378 us; speedup 1.0000x reference)
//
#include <hip/hip_runtime.h>
#include <math.h>

#define NG 100
#define ND 200
#define NLINE 500
#define NB 300
#define NW 50
#define NS 128
#define NX 500          // n = 3G + D
#define CVIOL 20000.0f
#define NITERS 600
#define PITERS 50

// workspace layout (float offsets)
#define OFF_HGL    0          // 500*300
#define OFF_HGLT   150000     // 300*500
#define OFF_B      300000     // 300*300
#define OFF_HWT    390000     // 50*500
#define OFF_QC     415000     // 128*500
#define OFF_QD     479000     // 128*500
#define OFF_RUP    543000     // 100
#define OFF_RDN    543100     // 100
#define OFF_FUP    543200     // 500
#define OFF_FDN    543700     // 500
#define OFF_QE     544200     // 128
#define OFF_STEP   544328     // 1
#define OFF_BUS    544332     // 300 ints
#define OFF_BUSW   544632     // 50 ints

// ---------------------------------------------------------------- K1: small precompute
__global__ __launch_bounds__(512) void k_pre(
    const float* __restrict__ p_da, const float* __restrict__ r_up_hat,
    const float* __restrict__ r_down_hat, const float* __restrict__ fup_hat,
    const float* __restrict__ fdn_hat, const float* __restrict__ w_err,
    const float* __restrict__ Pmax, const float* __restrict__ nG,
    const float* __restrict__ nL, const float* __restrict__ nW, float* ws) {
  const int t = threadIdx.x;
  int* bus  = (int*)(ws + OFF_BUS);
  int* busW = (int*)(ws + OFF_BUSW);
  if (t < NG) {
    int bf = 0;
    for (int b = 0; b < NB; ++b) if (nG[b*NG + t] > 0.5f) bf = b;
    bus[t] = bf;
    ws[OFF_RUP + t] = fmaxf(fminf(r_up_hat[t], Pmax[t] - p_da[t]), 0.f);
    ws[OFF_RDN + t] = fmaxf(fminf(r_down_hat[t], p_da[t]), 0.f);
  }
  if (t < ND) {
    int bf = 0;
    for (int b = 0; b < NB; ++b) if (nL[b*ND + t] > 0.5f) bf = b;
    bus[NG + t] = bf;
  }
  if (t < NW) {
    int bf = 0;
    for (int b = 0; b < NB; ++b) if (nW[b*NW + t] > 0.5f) bf = b;
    busW[t] = bf;
  }
  if (t < NLINE) {
    ws[OFF_FUP + t] = fmaxf(fup_hat[t], 0.f);
    ws[OFF_FDN + t] = fmaxf(fdn_hat[t], 0.f);
  }
  if (t < NS) {
    float s = 0.f;
    for (int w = 0; w < NW; ++w) s += w_err[t*NW + w];
    ws[OFF_QE + t] = -s;
  }
}

// ---------------------------------------------------------------- K2: gather Hgl, HglT, HwT
__global__ __launch_bounds__(384) void k_buildH(const float* __restrict__ PTDF, float* ws) {
  const int l = blockIdx.x;
  const int t = threadIdx.x;
  const int* bus  = (const int*)(ws + OFF_BUS);
  const int* busW = (const int*)(ws + OFF_BUSW);
  if (t < NB) {
    const float val = PTDF[l*NB + bus[t]];
    ws[OFF_HGL  + l*NB + t]    = val;
    ws[OFF_HGLT + t*NLINE + l] = val;
  } else if (t < NB + NW) {
    const int w = t - NB;
    ws[OFF_HWT + w*NLINE + l] = PTDF[l*NB + busW[w]];
  }
}

// ---------------------------------------------------------------- K3: B = Hgl^T Hgl (300x300)
__global__ __launch_bounds__(320) void k_buildB(float* ws) {
  const int e = blockIdx.x;
  const int f = threadIdx.x;
  if (f >= NB) return;
  const float* __restrict__ H = ws + OFF_HGL;
  float acc = 0.f;
  #pragma unroll 4
  for (int l = 0; l < NLINE; ++l)
    acc = fmaf(H[l*NB + e], H[l*NB + f], acc);
  ws[OFF_B + e*NB + f] = acc;
}

// ---------------------------------------------------------------- K4: power iteration -> step
__global__ __launch_bounds__(512) void k_power(float* ws) {
  __shared__ __align__(16) float v[NX];
  __shared__ __align__(16) float q3[NB];
  __shared__ float Bq[NB];
  __shared__ float sE, sS;
  const int t = threadIdx.x;
  const float* __restrict__ B = ws + OFF_B;
  if (t < NX) v[t] = 1.0f / sqrtf(500.0f);
  __syncthreads();
  float s_last = 1.f;
  for (int it = 0; it < PITERS; ++it) {
    if (t < NG) q3[t] = v[t] - v[NG + t] - v[2*NG + t];
    else if (t < NB) q3[t] = v[t + 200];    // t in [100,300) -> v[300..500)
    __syncthreads();
    if (t < NB) {
      float acc = 0.f;
      const float4* q34 = (const float4*)q3;
      for (int k4 = 0; k4 < NB/4; ++k4) {
        const float4 qv = q34[k4];
        const float* bp = B + (k4*4)*NB + t;   // symmetric B: row k, col t (coalesced)
        acc = fmaf(bp[0],    qv.x, acc);
        acc = fmaf(bp[NB],   qv.y, acc);
        acc = fmaf(bp[2*NB], qv.z, acc);
        acc = fmaf(bp[3*NB], qv.w, acc);
      }
      Bq[t] = acc;
    }
    if (t < 64) {
      float p = 0.f;
      for (int k = t; k < NB; k += 64) p += q3[k];
      for (int o = 32; o; o >>= 1) p += __shfl_down(p, o);
      if (t == 0) sE = p;
    }
    __syncthreads();
    const float E = sE;
    if (t < NX) {
      float nv;
      if (t < NG)        nv = v[t] + 2.f*Bq[t] + E;
      else if (t < 2*NG) nv = v[t] - 2.f*Bq[t - NG] - E;
      else if (t < 3*NG) nv = -2.f*Bq[t - 2*NG] - E;
      else               nv = 2.f*Bq[NG + t - 3*NG] + E;
      v[t] = nv;
    }
    __syncthreads();
    if (t < 64) {
      float p = 0.f;
      for (int k = t; k < NX; k += 64) p += v[k]*v[k];
      for (int o = 32; o; o >>= 1) p += __shfl_down(p, o);
      if (t == 0) sS = p;
    }
    __syncthreads();
    const float sn = sqrtf(sS);
    if (t < NX) v[t] /= sn;
    s_last = sn;
    __syncthreads();
  }
  if (t == 0) ws[OFF_STEP] = 0.9f / sqrtf(s_last);
}

// ---------------------------------------------------------------- K5: qC,qD per scenario
__global__ __launch_bounds__(512) void k_buildq(const float* __restrict__ w_err, float* ws) {
  const int s = blockIdx.x;
  const int t = threadIdx.x;
  __shared__ float wsh[NW];
  if (t < NW) wsh[t] = w_err[s*NW + t];
  __syncthreads();
  if (t < NLINE) {
    float wh = 0.f;
    #pragma unroll
    for (int w = 0; w < NW; ++w)
      wh = fmaf(wsh[w], ws[OFF_HWT + w*NLINE + t], wh);
    ws[OFF_QC + s*NLINE + t] = ws[OFF_FUP + t] - wh;
    ws[OFF_QD + s*NLINE + t] = ws[OFF_FDN + t] + wh;
  }
}

// ---------------------------------------------------------------- K6: PDHG, one block per scenario
__global__ __launch_bounds__(1024) void k_pdhg(const float* __restrict__ ws, float* __restrict__ out) {
  __shared__ __align__(16) float x[NX];
  __shared__ __align__(16) float z[NX];
  __shared__ __align__(16) float u[NLINE];
  __shared__ __align__(16) float zs[NB];
  __shared__ __align__(16) float Cv[NLINE];
  __shared__ __align__(16) float fpart[NLINE];
  __shared__ __align__(16) float tpart[3][NB];
  __shared__ float yA[NG], yB[NG], yCs[NLINE], yDs[NLINE];
  __shared__ float qA[NG], qB[NG], qC[NLINE], qD[NLINE];
  __shared__ float sE, sYE;

  const int t = threadIdx.x;
  const int s = blockIdx.x;
  const float step = ws[OFF_STEP];
  const float qE = ws[OFF_QE + s];
  const float* __restrict__ HGL  = ws + OFF_HGL;
  const float* __restrict__ HGLT = ws + OFF_HGLT;

  if (t < NX) { x[t] = 0.f; z[t] = 0.f; }
  if (t < NLINE) {
    u[t] = 0.f; yCs[t] = 0.f; yDs[t] = 0.f;
    qC[t] = ws[OFF_QC + s*NLINE + t];
    qD[t] = ws[OFF_QD + s*NLINE + t];
  }
  if (t < NG) { yA[t] = 0.f; yB[t] = 0.f; qA[t] = ws[OFF_RUP + t]; qB[t] = ws[OFF_RDN + t]; }
  if (t == 0) { sYE = 0.f; sE = 0.f; }
  __syncthreads();

  const int h3 = t / 300;          // phase A: 3-way row split
  const int c3 = t - h3*300;
  const int hc = t / 500;          // phase C: 2-way col split
  const int rc = t - hc*500;

  for (int it = 0; it < NITERS; ++it) {
    // Phase A: tpart[h][c] = sum_{l in rows(h)} Hgl[l,c] * u[l]
    if (t < 900) {
      const int l0 = h3*168;
      const int l1 = (h3 == 2) ? 500 : (l0 + 168);
      float acc = 0.f;
      const float4* u4 = (const float4*)u;
      for (int l4 = (l0 >> 2); l4 < (l1 >> 2); ++l4) {
        const float4 uv = u4[l4];
        const float* hp = HGL + (l4 << 2)*NB + c3;
        acc = fmaf(hp[0],    uv.x, acc);
        acc = fmaf(hp[NB],   uv.y, acc);
        acc = fmaf(hp[2*NB], uv.z, acc);
        acc = fmaf(hp[3*NB], uv.w, acc);
      }
      tpart[h3][c3] = acc;
    }
    __syncthreads();
    // Phase B: x-update
    if (t < NX) {
      const float yE = sYE;
      float yK;
      if (t < NG) {
        const float tg = tpart[0][t] + tpart[1][t] + tpart[2][t];
        yK = yA[t] + tg + yE;
      } else if (t < 2*NG) {
        const int g = t - NG;
        const float tg = tpart[0][g] + tpart[1][g] + tpart[2][g];
        yK = yB[g] - tg - yE;
      } else if (t < 3*NG) {
        const int g = t - 2*NG;
        const float tg = tpart[0][g] + tpart[1][g] + tpart[2][g];
        yK = -tg - yE;
      } else {
        const int cc = NG + (t - 3*NG);
        const float tl = tpart[0][cc] + tpart[1][cc] + tpart[2][cc];
        yK = tl + yE;
      }
      const float cj = (t < 2*NG) ? 0.f : CVIOL;
      const float xo = x[t];
      const float x1 = fmaxf(xo - step*(cj + yK), 0.f);
      z[t] = 2.f*x1 - xo;
      x[t] = x1;
    }
    __syncthreads();
    // zs = [z1 - z2 - z3 ; z4]
    if (t < NG) zs[t] = z[t] - z[NG + t] - z[2*NG + t];
    else if (t < NB) zs[t] = z[t + 200];     // t in [100,300) -> z[300..500)
    __syncthreads();
    if (t < 64) {
      float p = 0.f;
      for (int k = t; k < NB; k += 64) p += zs[k];
      for (int o = 32; o; o >>= 1) p += __shfl_down(p, o);
      if (t == 0) sE = p;
    }
    // Phase C: Cv[r] = sum_c Hgl[r,c]*zs[c] via HglT (coalesced over r)
    if (t < 1000) {
      const int c0 = hc ? 152 : 0;
      const int c1 = hc ? 300 : 152;
      float acc = 0.f;
      const float4* zs4 = (const float4*)zs;
      for (int c4 = (c0 >> 2); c4 < (c1 >> 2); ++c4) {
        const float4 zv = zs4[c4];
        const float* hp = HGLT + (c4 << 2)*NLINE + rc;
        acc = fmaf(hp[0],        zv.x, acc);
        acc = fmaf(hp[NLINE],    zv.y, acc);
        acc = fmaf(hp[2*NLINE],  zv.z, acc);
        acc = fmaf(hp[3*NLINE],  zv.w, acc);
      }
      if (hc == 0) Cv[rc] = acc; else fpart[rc] = acc;
    }
    __syncthreads();
    // Phase D: y-update (+ u for next iter)
    if (t < NLINE) {
      const float cv = Cv[t] + fpart[t];
      const float cy = fmaxf(yCs[t] + step*( cv - qC[t]), 0.f);
      const float dy = fmaxf(yDs[t] + step*(-cv - qD[t]), 0.f);
      yCs[t] = cy; yDs[t] = dy; u[t] = cy - dy;
    } else if (t >= 512 && t < 512 + NG) {
      const int g = t - 512;
      yA[g] = fmaxf(yA[g] + step*(z[g] - qA[g]), 0.f);
    } else if (t >= 640 && t < 640 + NG) {
      const int g = t - 640;
      yB[g] = fmaxf(yB[g] + step*(z[NG + g] - qB[g]), 0.f);
    } else if (t == 1023) {
      sYE += step*(sE - qE);
    }
    __syncthreads();
  }
  // cost = CVIOL * sum(x[200:500])
  if (t < 64) {
    float p = 0.f;
    for (int k = 200 + t; k < NX; k += 64) p += x[k];
    for (int o = 32; o; o >>= 1) p += __shfl_down(p, o);
    if (t == 0) out[s] = CVIOL * p;
  }
}

extern "C" void kernel_launch(void* const* d_in, const int* in_sizes, int n_in,
                              void* d_out, int out_size, void* d_ws, size_t ws_size,
                              hipStream_t stream) {
  (void)in_sizes; (void)n_in; (void)out_size; (void)ws_size;
  const float* p_da      = (const float*)d_in[0];
  const float* r_up_hat  = (const float*)d_in[1];
  const float* r_dn_hat  = (const float*)d_in[2];
  const float* fup_hat   = (const float*)d_in[3];
  const float* fdn_hat   = (const float*)d_in[4];
  const float* w_err     = (const float*)d_in[5];
  const float* Pmax      = (const float*)d_in[6];
  const float* PTDF      = (const float*)d_in[7];
  const float* nG        = (const float*)d_in[8];
  const float* nL        = (const float*)d_in[9];
  const float* nW        = (const float*)d_in[10];
  float* ws  = (float*)d_ws;
  float* out = (float*)d_out;

  hipLaunchKernelGGL(k_pre,    dim3(1),   dim3(512), 0, stream,
                     p_da, r_up_hat, r_dn_hat, fup_hat, fdn_hat, w_err, Pmax, nG, nL, nW, ws);
  hipLaunchKernelGGL(k_buildH, dim3(500), dim3(384), 0, stream, PTDF, ws);
  hipLaunchKernelGGL(k_buildB, dim3(300), dim3(320), 0, stream, ws);
  hipLaunchKernelGGL(k_power,  dim3(1),   dim3(512), 0, stream, ws);
  hipLaunchKernelGGL(k_buildq, dim3(128), dim3(512), 0, stream, w_err, ws);
  hipLaunchKernelGGL(k_pdhg,   dim3(128), dim3(1024), 0, stream, ws, out);
}

// Round 2
// 5561.913 us; speedup vs baseline: 1.2441x; 1.2441x over previous
//
#include <hip/hip_runtime.h>
#include <math.h>

#define NG 100
#define ND 200
#define NLINE 500
#define NB 300
#define NW 50
#define NS 128
#define NX 500
#define CVIOL 20000.0f
#define NITERS 600
#define PITERS 50

#define NUPAD_MAX 304
#define HS_STRIDE 304
#define HST_STRIDE 512

// workspace layout (float offsets)
#define OFF_HS     0          // 500*304
#define OFF_HST    152000     // 304*512
#define OFF_B      307648     // 300*300
#define OFF_HWT    397648     // 50*500
#define OFF_QC     422648     // 128*500
#define OFF_QD     486648     // 128*500
#define OFF_RUP    550648     // 100
#define OFF_RDN    550748     // 100
#define OFF_FUP    550848     // 500
#define OFF_FDN    551348     // 500
#define OFF_QE     551848     // 128
#define OFF_STEP   551976     // 1
#define OFF_NU     551977     // 1 int
#define OFF_NUP    551978     // 1 int
#define OFF_BUS    551980     // 300 ints
#define OFF_BUSW   552280     // 50 ints
#define OFF_UBUS   552330     // 304 ints
#define OFF_C2U    552634     // 300 ints
#define OFF_CUS    552934     // 305 ints
#define OFF_CUL    553239     // 300 ints

// ---------------------------------------------------------------- K1: precompute + unique-bus build
__global__ __launch_bounds__(512) void k_pre(
    const float* __restrict__ p_da, const float* __restrict__ r_up_hat,
    const float* __restrict__ r_down_hat, const float* __restrict__ fup_hat,
    const float* __restrict__ fdn_hat, const float* __restrict__ w_err,
    const float* __restrict__ Pmax, const float* __restrict__ nG,
    const float* __restrict__ nL, const float* __restrict__ nW, float* ws) {
  const int t = threadIdx.x;
  int* bus  = (int*)(ws + OFF_BUS);
  int* busW = (int*)(ws + OFF_BUSW);
  if (t < NG) {
    int bf = 0;
    for (int b = 0; b < NB; ++b) if (nG[b*NG + t] > 0.5f) bf = b;
    bus[t] = bf;
    ws[OFF_RUP + t] = fmaxf(fminf(r_up_hat[t], Pmax[t] - p_da[t]), 0.f);
    ws[OFF_RDN + t] = fmaxf(fminf(r_down_hat[t], p_da[t]), 0.f);
  }
  if (t < ND) {
    int bf = 0;
    for (int b = 0; b < NB; ++b) if (nL[b*ND + t] > 0.5f) bf = b;
    bus[NG + t] = bf;
  }
  if (t < NW) {
    int bf = 0;
    for (int b = 0; b < NB; ++b) if (nW[b*NW + t] > 0.5f) bf = b;
    busW[t] = bf;
  }
  if (t < NLINE) {
    ws[OFF_FUP + t] = fmaxf(fup_hat[t], 0.f);
    ws[OFF_FDN + t] = fmaxf(fdn_hat[t], 0.f);
  }
  if (t < NS) {
    float s = 0.f;
    for (int w = 0; w < NW; ++w) s += w_err[t*NW + w];
    ws[OFF_QE + t] = -s;
  }
  __syncthreads();
  if (t == 0) {
    int uidx[NB];
    int cnt[NUPAD_MAX];
    int* ubus = (int*)(ws + OFF_UBUS);
    int* c2u  = (int*)(ws + OFF_C2U);
    int* cus  = (int*)(ws + OFF_CUS);
    int* cul  = (int*)(ws + OFF_CUL);
    for (int b = 0; b < NB; ++b) uidx[b] = -1;
    int nu = 0;
    for (int c = 0; c < NB; ++c) {
      const int b = bus[c];
      if (uidx[b] < 0) { uidx[b] = nu; ubus[nu] = b; nu++; }
      c2u[c] = uidx[b];
    }
    const int nup = (nu + 7) & ~7;
    for (int u = nu; u < nup; ++u) ubus[u] = 0;
    ((int*)(ws + OFF_NU))[0]  = nu;
    ((int*)(ws + OFF_NUP))[0] = nup;
    for (int u = 0; u < nup; ++u) cnt[u] = 0;
    for (int c = 0; c < NB; ++c) cnt[c2u[c]]++;
    int acc = 0;
    for (int u = 0; u < nup; ++u) { cus[u] = acc; acc += cnt[u]; cnt[u] = cus[u]; }
    cus[nup] = acc;
    for (int c = 0; c < NB; ++c) cul[cnt[c2u[c]]++] = c;
  }
}

// ---------------------------------------------------------------- K2: gather Hs, HsT, HwT
__global__ __launch_bounds__(384) void k_buildH(const float* __restrict__ PTDF, float* ws) {
  const int l = blockIdx.x;
  const int t = threadIdx.x;
  const int NU  = ((const int*)(ws + OFF_NU))[0];
  const int NUP = ((const int*)(ws + OFF_NUP))[0];
  const int* ubus = (const int*)(ws + OFF_UBUS);
  const int* busW = (const int*)(ws + OFF_BUSW);
  if (t < NUPAD_MAX) {
    const float val = (t < NU) ? PTDF[l*NB + ubus[t]] : 0.f;
    ws[OFF_HS + l*HS_STRIDE + t] = val;
    if (t < NUP) {
      ws[OFF_HST + t*HST_STRIDE + l] = val;
      if (l == 0) {
        for (int ll = NLINE; ll < HST_STRIDE; ++ll)
          ws[OFF_HST + t*HST_STRIDE + ll] = 0.f;
      }
    }
  } else if (t < NUPAD_MAX + NW) {
    const int w = t - NUPAD_MAX;
    ws[OFF_HWT + w*NLINE + l] = PTDF[l*NB + busW[w]];
  }
}

// ---------------------------------------------------------------- K3: B[e,f] = Hgl col_e . col_f
__global__ __launch_bounds__(320) void k_buildB(float* ws) {
  const int e = blockIdx.x;
  const int f = threadIdx.x;
  if (f >= NB) return;
  const int* c2u = (const int*)(ws + OFF_C2U);
  const float* __restrict__ re = ws + OFF_HST + c2u[e]*HST_STRIDE;
  const float* __restrict__ rf = ws + OFF_HST + c2u[f]*HST_STRIDE;
  float acc = 0.f;
  #pragma unroll 4
  for (int l = 0; l < NLINE; ++l)
    acc = fmaf(re[l], rf[l], acc);
  ws[OFF_B + e*NB + f] = acc;
}

// ---------------------------------------------------------------- K4: power iteration -> step
__global__ __launch_bounds__(512) void k_power(float* ws) {
  __shared__ __align__(16) float v[NX];
  __shared__ __align__(16) float q3[NB];
  __shared__ float Bq[NB];
  __shared__ float sE, sS;
  const int t = threadIdx.x;
  const float* __restrict__ B = ws + OFF_B;
  if (t < NX) v[t] = 1.0f / sqrtf(500.0f);
  __syncthreads();
  float s_last = 1.f;
  for (int it = 0; it < PITERS; ++it) {
    if (t < NG) q3[t] = v[t] - v[NG + t] - v[2*NG + t];
    else if (t < NB) q3[t] = v[t + 200];
    __syncthreads();
    if (t < NB) {
      float acc = 0.f;
      const float4* q34 = (const float4*)q3;
      for (int k4 = 0; k4 < NB/4; ++k4) {
        const float4 qv = q34[k4];
        const float* bp = B + (k4*4)*NB + t;
        acc = fmaf(bp[0],    qv.x, acc);
        acc = fmaf(bp[NB],   qv.y, acc);
        acc = fmaf(bp[2*NB], qv.z, acc);
        acc = fmaf(bp[3*NB], qv.w, acc);
      }
      Bq[t] = acc;
    }
    if (t < 64) {
      float p = 0.f;
      for (int k = t; k < NB; k += 64) p += q3[k];
      for (int o = 32; o; o >>= 1) p += __shfl_down(p, o);
      if (t == 0) sE = p;
    }
    __syncthreads();
    const float E = sE;
    if (t < NX) {
      float nv;
      if (t < NG)        nv = v[t] + 2.f*Bq[t] + E;
      else if (t < 2*NG) nv = v[t] - 2.f*Bq[t - NG] - E;
      else if (t < 3*NG) nv = -2.f*Bq[t - 2*NG] - E;
      else               nv = 2.f*Bq[NG + t - 3*NG] + E;
      v[t] = nv;
    }
    __syncthreads();
    if (t < 64) {
      float p = 0.f;
      for (int k = t; k < NX; k += 64) p += v[k]*v[k];
      for (int o = 32; o; o >>= 1) p += __shfl_down(p, o);
      if (t == 0) sS = p;
    }
    __syncthreads();
    const float sn = sqrtf(sS);
    if (t < NX) v[t] /= sn;
    s_last = sn;
    __syncthreads();
  }
  if (t == 0) ws[OFF_STEP] = 0.9f / sqrtf(s_last);
}

// ---------------------------------------------------------------- K5: qC,qD per scenario
__global__ __launch_bounds__(512) void k_buildq(const float* __restrict__ w_err, float* ws) {
  const int s = blockIdx.x;
  const int t = threadIdx.x;
  __shared__ float wsh[NW];
  if (t < NW) wsh[t] = w_err[s*NW + t];
  __syncthreads();
  if (t < NLINE) {
    float wh = 0.f;
    #pragma unroll
    for (int w = 0; w < NW; ++w)
      wh = fmaf(wsh[w], ws[OFF_HWT + w*NLINE + t], wh);
    ws[OFF_QC + s*NLINE + t] = ws[OFF_FUP + t] - wh;
    ws[OFF_QD + s*NLINE + t] = ws[OFF_FDN + t] + wh;
  }
}

// ---------------------------------------------------------------- K6: PDHG, 2 scenarios per block
__global__ __launch_bounds__(1024) void k_pdhg(const float* __restrict__ ws, float* __restrict__ out) {
  __shared__ __align__(16) float scratch[8448];   // union: tpart[lg][u][2] / fpart[ug][l][2]
  __shared__ __align__(16) float xs[2][512];
  __shared__ __align__(16) float zsh[2][512];
  __shared__ __align__(16) float uu[2][512];
  __shared__ __align__(16) float busz[2][NUPAD_MAX];
  __shared__ float yA[2][NG], yB[2][NG];
  __shared__ float yC[2][512], yD[2][512];
  __shared__ float qC[2][512], qD[2][512];
  __shared__ float qA[NG], qB[NG];
  __shared__ float sYE[2];
  __shared__ float eparts[16];
  __shared__ int c2u_s[NB];
  __shared__ int cus_s[NUPAD_MAX + 1];
  __shared__ int cul_s[NB];

  const int t = threadIdx.x;
  const int s0 = blockIdx.x * 2;
  const float step = ws[OFF_STEP];
  const int NUP = ((const int*)(ws + OFF_NUP))[0];
  const float qE0 = ws[OFF_QE + s0];
  const float qE1 = ws[OFF_QE + s0 + 1];
  const float* __restrict__ HS  = ws + OFF_HS;
  const float* __restrict__ HST = ws + OFF_HST;

  // ---- init
  if (t < 512) {
    #pragma unroll
    for (int s = 0; s < 2; ++s) {
      xs[s][t] = 0.f; zsh[s][t] = 0.f; uu[s][t] = 0.f;
      yC[s][t] = 0.f; yD[s][t] = 0.f;
      const float vc = (t < NLINE) ? ws[OFF_QC + (s0+s)*NLINE + t] : 0.f;
      const float vd = (t < NLINE) ? ws[OFF_QD + (s0+s)*NLINE + t] : 0.f;
      qC[s][t] = vc; qD[s][t] = vd;
    }
  }
  if (t < NG) {
    yA[0][t]=0.f; yA[1][t]=0.f; yB[0][t]=0.f; yB[1][t]=0.f;
    qA[t] = ws[OFF_RUP + t]; qB[t] = ws[OFF_RDN + t];
  }
  if (t < NB) {
    c2u_s[t] = ((const int*)(ws + OFF_C2U))[t];
    cul_s[t] = ((const int*)(ws + OFF_CUL))[t];
  }
  if (t <= NUP) cus_s[t] = ((const int*)(ws + OFF_CUS))[t];
  if (t < 2) sYE[t] = 0.f;

  // ---- phase thread mappings (runtime NUP)
  const int ncol4 = NUP >> 2;
  const int nlg   = 1024 / ncol4;
  const int cg    = t % ncol4;
  const int lg    = t / ncol4;
  const bool aAct = (lg < nlg);
  const int r0 = aAct ? (lg * NLINE) / nlg : 0;
  const int r1 = aAct ? ((lg + 1) * NLINE) / nlg : 0;
  const int l4 = t % 125;
  const int ug = t / 125;
  const int nuchunk = NUP >> 3;
  const int u0 = ug * nuchunk;
  __syncthreads();

  for (int it = 0; it < NITERS; ++it) {
    // ---- Phase A: tpart[lg][u][s] partial of Hs^T * u
    if (aAct) {
      float4 a0 = {0.f,0.f,0.f,0.f}, a1 = {0.f,0.f,0.f,0.f};
      #pragma unroll 4
      for (int l = r0; l < r1; ++l) {
        const float4 h = *(const float4*)(HS + l*HS_STRIDE + 4*cg);
        const float w0 = uu[0][l];
        const float w1 = uu[1][l];
        a0.x = fmaf(h.x, w0, a0.x); a0.y = fmaf(h.y, w0, a0.y);
        a0.z = fmaf(h.z, w0, a0.z); a0.w = fmaf(h.w, w0, a0.w);
        a1.x = fmaf(h.x, w1, a1.x); a1.y = fmaf(h.y, w1, a1.y);
        a1.z = fmaf(h.z, w1, a1.z); a1.w = fmaf(h.w, w1, a1.w);
      }
      float* sp = scratch + ((lg*NUP + 4*cg) << 1);
      sp[0]=a0.x; sp[2]=a0.y; sp[4]=a0.z; sp[6]=a0.w;
      sp[1]=a1.x; sp[3]=a1.y; sp[5]=a1.z; sp[7]=a1.w;
    }
    __syncthreads();
    // ---- x-update (inline reduce over lg)
    if (t < 1000) {
      const int s = t & 1, c = t >> 1;
      const int cc  = (c < NB) ? (c % NG) : (c - 200);
      const int uix = c2u_s[cc];
      float tg = 0.f;
      const float* sp = scratch + (uix << 1) + s;
      const int stride = NUP << 1;
      for (int g = 0; g < nlg; ++g) tg += sp[g * stride];
      const float yE = sYE[s];
      float yK;
      if (c < NG)            yK = yA[s][c] + tg + yE;
      else if (c < 2*NG)     yK = yB[s][c - NG] - tg - yE;
      else if (c < 3*NG)     yK = -tg - yE;
      else                   yK = tg + yE;
      const float cj = (c < 2*NG) ? 0.f : CVIOL;
      const float xo = xs[s][c];
      const float x1 = fmaxf(xo - step*(cj + yK), 0.f);
      zsh[s][c] = 2.f*x1 - xo;
      xs[s][c]  = x1;
    }
    __syncthreads();
    // ---- busz[u][s] = sum of zs components mapping to unique bus u
    if (t < (NUP << 1)) {
      const int s = t & 1, u = t >> 1;
      float acc = 0.f;
      const int k0 = cus_s[u], k1 = cus_s[u+1];
      for (int k = k0; k < k1; ++k) {
        const int c = cul_s[k];
        acc += (c < NG) ? (zsh[s][c] - zsh[s][NG + c] - zsh[s][2*NG + c])
                        : zsh[s][200 + c];
      }
      busz[s][u] = acc;
    }
    __syncthreads();
    // ---- Phase C: fpart[ug][l][s] partial of Hs * busz; plus E partials
    if (t < 1000) {
      float4 a0 = {0.f,0.f,0.f,0.f}, a1 = {0.f,0.f,0.f,0.f};
      const int uend = u0 + nuchunk;
      #pragma unroll 4
      for (int u = u0; u < uend; ++u) {
        const float4 h = *(const float4*)(HST + u*HST_STRIDE + 4*l4);
        const float b0 = busz[0][u];
        const float b1 = busz[1][u];
        a0.x = fmaf(h.x, b0, a0.x); a0.y = fmaf(h.y, b0, a0.y);
        a0.z = fmaf(h.z, b0, a0.z); a0.w = fmaf(h.w, b0, a0.w);
        a1.x = fmaf(h.x, b1, a1.x); a1.y = fmaf(h.y, b1, a1.y);
        a1.z = fmaf(h.z, b1, a1.z); a1.w = fmaf(h.w, b1, a1.w);
      }
      float* sp = scratch + ((ug*NLINE + 4*l4) << 1);
      sp[0]=a0.x; sp[2]=a0.y; sp[4]=a0.z; sp[6]=a0.w;
      sp[1]=a1.x; sp[3]=a1.y; sp[5]=a1.z; sp[7]=a1.w;
    } else if (t < 1016) {
      const int j = t - 1000, s = j & 1, part = j >> 1;
      float acc = 0.f;
      const int ua = part * nuchunk, ub = ua + nuchunk;
      for (int u = ua; u < ub; ++u) acc += busz[s][u];
      eparts[j] = acc;
    }
    __syncthreads();
    // ---- y-update (inline reduce over ug) + yA/yB + yE
    if (t < 1000) {
      const int s = t & 1, l = t >> 1;
      float cv = 0.f;
      const float* sp = scratch + (l << 1) + s;
      #pragma unroll
      for (int g = 0; g < 8; ++g) cv += sp[g * 1000];
      const float cy = fmaxf(yC[s][l] + step*( cv - qC[s][l]), 0.f);
      const float dy = fmaxf(yD[s][l] + step*(-cv - qD[s][l]), 0.f);
      yC[s][l] = cy; yD[s][l] = dy; uu[s][l] = cy - dy;
    }
    if (t < 400) {
      const int s = t & 1, g = (t >> 1) % NG, w = (t >> 1) / NG;
      if (w == 0) yA[s][g] = fmaxf(yA[s][g] + step*(zsh[s][g]      - qA[g]), 0.f);
      else        yB[s][g] = fmaxf(yB[s][g] + step*(zsh[s][NG + g] - qB[g]), 0.f);
    }
    if (t == 1023) {
      float e0 = 0.f, e1 = 0.f;
      #pragma unroll
      for (int p = 0; p < 8; ++p) { e0 += eparts[p*2]; e1 += eparts[p*2 + 1]; }
      sYE[0] += step*(e0 - qE0);
      sYE[1] += step*(e1 - qE1);
    }
    __syncthreads();
  }
  // ---- cost = CVIOL * sum(x[200:500])
  if (t < 128) {
    const int s = t >> 6, lane = t & 63;
    float p = 0.f;
    for (int k = 200 + lane; k < NX; k += 64) p += xs[s][k];
    for (int o = 32; o; o >>= 1) p += __shfl_down(p, o);
    if (lane == 0) out[s0 + s] = CVIOL * p;
  }
}

extern "C" void kernel_launch(void* const* d_in, const int* in_sizes, int n_in,
                              void* d_out, int out_size, void* d_ws, size_t ws_size,
                              hipStream_t stream) {
  (void)in_sizes; (void)n_in; (void)out_size; (void)ws_size;
  const float* p_da      = (const float*)d_in[0];
  const float* r_up_hat  = (const float*)d_in[1];
  const float* r_dn_hat  = (const float*)d_in[2];
  const float* fup_hat   = (const float*)d_in[3];
  const float* fdn_hat   = (const float*)d_in[4];
  const float* w_err     = (const float*)d_in[5];
  const float* Pmax      = (const float*)d_in[6];
  const float* PTDF      = (const float*)d_in[7];
  const float* nG        = (const float*)d_in[8];
  const float* nL        = (const float*)d_in[9];
  const float* nW        = (const float*)d_in[10];
  float* ws  = (float*)d_ws;
  float* out = (float*)d_out;

  hipLaunchKernelGGL(k_pre,    dim3(1),   dim3(512), 0, stream,
                     p_da, r_up_hat, r_dn_hat, fup_hat, fdn_hat, w_err, Pmax, nG, nL, nW, ws);
  hipLaunchKernelGGL(k_buildH, dim3(500), dim3(384), 0, stream, PTDF, ws);
  hipLaunchKernelGGL(k_buildB, dim3(300), dim3(320), 0, stream, ws);
  hipLaunchKernelGGL(k_power,  dim3(1),   dim3(512), 0, stream, ws);
  hipLaunchKernelGGL(k_buildq, dim3(128), dim3(512), 0, stream, w_err, ws);
  hipLaunchKernelGGL(k_pdhg,   dim3(64),  dim3(1024), 0, stream, ws, out);
}